// Round 4
// baseline (243.534 us; speedup 1.0000x reference)
//
#include <hip/hip_runtime.h>
#include <math.h>

#define B_ 64
#define T_ 256
#define K_ 128

typedef _Float16 half2v __attribute__((ext_vector_type(2)));
typedef const __attribute__((address_space(1))) void* gas1_t;
typedef __attribute__((address_space(3))) void* las3_t;

static __device__ __forceinline__ half2v pack_h2(float a, float b) {
    return __builtin_bit_cast(half2v, __builtin_amdgcn_cvt_pkrtz(a, b));
}

// One WAVE per batch element: no __syncthreads anywhere in the scan loop.
// Lane (it = lane>>3, jt = lane&7) owns E rows [16it,16it+16) x cols [16jt,16jt+16)
// as 128 packed-fp16 half2 VGPRs. v (128 states) lives as 8 half2 regs per lane
// (cols of its jt group), replicated across the 8 it-groups.
// Per step: 128 v_dot2_f32_f16 -> 3-level jt-butterfly (rows 16it+2jt+{0,1}) ->
// exp(y)*u with per-step rescale (sum from previous step, overlapped) ->
// pack to half2 -> 8-shuffle transpose re-gather of next v. fp16 v is safe:
// values bounded by e^{max y + max trans} ~ 1.5e4 < 65504 after per-step rescale.
__global__ __launch_bounds__(64) void crf_fwd_kernel(
    const float* __restrict__ y,
    const float* __restrict__ mask,
    const float* __restrict__ trans,
    float* __restrict__ out)
{
    const int b    = blockIdx.x;
    const int lane = threadIdx.x;        // 0..63, one wave
    const int it   = lane >> 3;          // 0..7 : row group
    const int jt   = lane & 7;           // 0..7 : col group
    const bool j0  = (jt & 1) != 0;
    const bool j1  = (jt & 2) != 0;
    const bool j2  = (jt & 4) != 0;

    __shared__ __align__(16) float ybuf[2][32 * K_];   // 2 x 16 KB y chunks

    const float* yb = y + (size_t)b * (T_ * K_);

    // async chunk staging: chunk c (32 steps x 128 floats) -> ybuf[buf]
    auto stage = [&](int c, int buf) {
        const float* gp = yb + (size_t)c * (32 * K_);
        #pragma unroll
        for (int s = 0; s < 16; ++s) {
            __builtin_amdgcn_global_load_lds(
                (gas1_t)(gp + s * 256 + lane * 4),
                (las3_t)(&ybuf[buf][s * 256]),
                16, 0, 0);
        }
    };

    stage(0, 0);

    // ---- sequence length: mask is 1.0/0.0 and contiguous ----
    float4 mv = *(const float4*)(mask + b * T_ + (lane << 2));
    float lc = (mv.x + mv.y) + (mv.z + mv.w);
    lc += __shfl_xor(lc, 1);
    lc += __shfl_xor(lc, 2);
    lc += __shfl_xor(lc, 4);
    lc += __shfl_xor(lc, 8);
    lc += __shfl_xor(lc, 16);
    lc += __shfl_xor(lc, 32);
    const int L = (int)lc;               // wave-uniform

    // ---- E tile: E[r][q] = fp16x2{ exp(trans[16it+r][16jt+2q]), ...+1 } ----
    half2v E[16][8];
    #pragma unroll
    for (int r = 0; r < 16; ++r) {
        const float* tp = trans + (it * 16 + r) * K_ + jt * 16;
        #pragma unroll
        for (int q = 0; q < 8; ++q) {
            float e0 = __expf(tp[2 * q]);
            float e1 = __expf(tp[2 * q + 1]);
            E[r][q] = pack_h2(e0, e1);
        }
    }

    // ---- v = one-hot SOS (state 2 = jt group 0, q=1, .x) ----
    half2v v[8];
    #pragma unroll
    for (int q = 0; q < 8; ++q) v[q] = half2v{(_Float16)0.0f, (_Float16)0.0f};
    if (jt == 0) v[1] = half2v{(_Float16)1.0f, (_Float16)0.0f};

    float c_acc = 0.0f;
    float S     = 1.0f;                  // sum of current stored v (wave-uniform)

    for (int t = 0; t < L; ++t) {
        const int g  = t >> 5;
        const int tt = t & 31;
        const int cb = g & 1;

        if (tt == 0) {                   // prefetch chunk g+1, wait for chunk g
            const int c2 = g + 1;
            if (c2 < 8) stage(c2, c2 & 1);
            asm volatile("s_waitcnt vmcnt(16)" ::: "memory");
        }

        // y for the two rows this lane finalizes: i0 = 16it + 2jt
        float2 yv = *(const float2*)&ybuf[cb][tt * K_ + (it << 4) + (jt << 1)];

        const float rinv = __builtin_amdgcn_rcpf(S);
        c_acc += __logf(S);

        // ---- 128 dot2: p[r] = sum over this lane's 16 cols ----
        float p[16];
        #pragma unroll
        for (int r = 0; r < 16; ++r) {
            float a = 0.0f;
            #pragma unroll
            for (int q = 0; q < 8; ++q)
                a = __builtin_amdgcn_fdot2(E[r][q], v[q], a, false);
            p[r] = a;
        }

        // ---- halving butterfly over jt: 16 -> 8 -> 4 -> 2 rows per lane ----
        // level 0 (xor1): fix row-bit1 = jt0
        float u8[8];
        const int m0l[8] = {0, 1, 4, 5, 8, 9, 12, 13};
        #pragma unroll
        for (int k = 0; k < 8; ++k) {
            const int m = m0l[k];
            float ka = p[m], kb = p[m + 2];
            float snd = j0 ? ka : kb;
            float kp  = j0 ? kb : ka;
            u8[k] = kp + __shfl_xor(snd, 1);
        }
        // level 1 (xor2): fix row-bit2 = jt1
        float u4[4];
        const int m1l[4] = {0, 1, 4, 5};
        #pragma unroll
        for (int k = 0; k < 4; ++k) {
            const int m = m1l[k];
            float ka = u8[m], kb = u8[m + 2];
            float snd = j1 ? ka : kb;
            float kp  = j1 ? kb : ka;
            u4[k] = kp + __shfl_xor(snd, 2);
        }
        // level 2 (xor4): fix row-bit3 = jt2 -> rows 16it + 2jt + {0,1}
        float u2[2];
        #pragma unroll
        for (int k = 0; k < 2; ++k) {
            float ka = u4[k], kb = u4[k + 2];
            float snd = j2 ? ka : kb;
            float kp  = j2 ? kb : ka;
            u2[k] = kp + __shfl_xor(snd, 4);
        }

        // ---- w = exp(y) * u / S_in ----
        float w0 = (__expf(yv.x) * rinv) * u2[0];
        float w1 = (__expf(yv.y) * rinv) * u2[1];

        // next S = sum of stored v (each state counted exactly once across 64 lanes);
        // 6-level chain overlaps the next iteration's dot phase
        float s01 = w0 + w1;
        s01 += __shfl_xor(s01, 1);
        s01 += __shfl_xor(s01, 2);
        s01 += __shfl_xor(s01, 4);
        s01 += __shfl_xor(s01, 8);
        s01 += __shfl_xor(s01, 16);
        s01 += __shfl_xor(s01, 32);
        S = s01;

        // ---- pack + transpose re-gather: v[q] <- pk from lane (jt<<3)|q ----
        half2v pk = pack_h2(w0, w1);
        int pki = __builtin_bit_cast(int, pk);
        #pragma unroll
        for (int q = 0; q < 8; ++q)
            v[q] = __builtin_bit_cast(half2v, __shfl(pki, (jt << 3) | q));
    }

    if (lane == 0) out[b] = c_acc + __logf(S);
}

extern "C" void kernel_launch(void* const* d_in, const int* in_sizes, int n_in,
                              void* d_out, int out_size, void* d_ws, size_t ws_size,
                              hipStream_t stream) {
    const float* y     = (const float*)d_in[0];   // (B, T, K) fp32
    const float* mask  = (const float*)d_in[1];   // (B, T)    fp32 0/1
    const float* trans = (const float*)d_in[2];   // (K, K)    fp32
    float* out = (float*)d_out;                    // (B,)      fp32
    crf_fwd_kernel<<<B_, 64, 0, stream>>>(y, mask, trans, out);
}

// Round 5
// 173.147 us; speedup vs baseline: 1.4065x; 1.4065x over previous
//
#include <hip/hip_runtime.h>
#include <math.h>

#define B_ 64
#define T_ 256
#define K_ 128
#define C_ 8           // chunks per batch
#define CL_ 32         // chunk length

typedef const __attribute__((address_space(1))) void* gas1_t;
typedef __attribute__((address_space(3))) void* las3_t;
typedef float  f32x4  __attribute__((ext_vector_type(4)));
typedef short  bf16x8 __attribute__((ext_vector_type(8)));
typedef unsigned int uintx4 __attribute__((ext_vector_type(4)));

// manual round-to-nearest-even fp32 -> bf16 (guaranteed to compile)
static __device__ __forceinline__ unsigned int bf16rne(float x) {
    unsigned int u = __builtin_bit_cast(unsigned int, x);
    return (u + 0x7FFFu + ((u >> 16) & 1u)) >> 16;
}
static __device__ __forceinline__ unsigned int pkbf16(float a, float b) {
    return bf16rne(a) | (bf16rne(b) << 16);
}

// ---------------- Phase 1: chunk products -------------------------------
// Block (b,c) computes P_c = prod_{t in chunk, t < L} diag(exp(y_t)) * E,
// column-sum-normalized per step (per-column log scales -> scalesWS).
// E (=exp(trans)) lives in registers as MFMA A-fragments (128 VGPRs/lane).
// P~ is 4 wave-private 32-column slabs in padded LDS (stride 272B -> 2-way
// bank aliasing only). ZERO barriers inside the 32-step scan loop.
// Export: P_c row-major bf16 (phase-2 B-operand layout) + per-column scales.
__global__ __launch_bounds__(256, 2) void crf_chunk_kernel(
    const float* __restrict__ y,
    const float* __restrict__ mask,
    const float* __restrict__ trans,
    unsigned short* __restrict__ matsWS,
    float* __restrict__ scalesWS)
{
    const int bc  = blockIdx.x;           // b*C_ + c
    const int b   = bc >> 3;
    const int c   = bc & 7;
    const int tid = threadIdx.x;
    const int w   = tid >> 6;             // wave 0..3 -> columns [32w, 32w+32)
    const int lane = tid & 63;
    const int g   = lane >> 4;            // quad 0..3
    const int ci  = lane & 15;

    __shared__ __align__(16) float eybuf[CL_ * K_];           // 16 KB: y then ey
    __shared__ __align__(16) unsigned short pbuf[4][32][136]; // 34.8 KB padded slabs
    __shared__ int lenS[4];

    // ---- DMA y chunk into LDS (16 segments x 1 KB) ----
    const float* gy = y + ((size_t)b * T_ + c * CL_) * K_;
    #pragma unroll
    for (int q = 0; q < 4; ++q) {
        const int seg = w * 4 + q;
        __builtin_amdgcn_global_load_lds((gas1_t)(gy + seg * 256 + lane * 4),
                                         (las3_t)(eybuf + seg * 256), 16, 0, 0);
    }

    // ---- sequence length (mask contiguous 1.0/0.0) ----
    float mval = mask[b * T_ + tid];
    unsigned long long bal = __ballot(mval != 0.0f);
    if (lane == 0) lenS[w] = __popcll(bal);

    // ---- E as A-fragments: E[rt][kt], A[m=ci][k = 8g + j] ----
    bf16x8 E[8][4];
    #pragma unroll
    for (int rt = 0; rt < 8; ++rt) {
        const float* tp = trans + (16 * rt + ci) * K_;
        #pragma unroll
        for (int kt = 0; kt < 4; ++kt) {
            f32x4 a = *(const f32x4*)(tp + 32 * kt + 8 * g);
            f32x4 bq = *(const f32x4*)(tp + 32 * kt + 8 * g + 4);
            uintx4 u;
            u.x = pkbf16(__expf(a.x), __expf(a.y));
            u.y = pkbf16(__expf(a.z), __expf(a.w));
            u.z = pkbf16(__expf(bq.x), __expf(bq.y));
            u.w = pkbf16(__expf(bq.z), __expf(bq.w));
            E[rt][kt] = __builtin_bit_cast(bf16x8, u);
        }
    }

    // ---- zero slabs ----
    for (int i = tid; i < 4 * 32 * 136; i += 256) ((unsigned short*)pbuf)[i] = 0;

    asm volatile("s_waitcnt vmcnt(0)" ::: "memory");   // y DMA done
    __syncthreads();

    // diag(I) + ey = exp(y) in place
    if (tid < K_) pbuf[tid >> 5][tid & 31][tid] = 0x3F80;   // bf16 1.0
    for (int i = tid; i < CL_ * K_; i += 256) eybuf[i] = __expf(eybuf[i]);
    __syncthreads();

    const int L = lenS[0] + lenS[1] + lenS[2] + lenS[3];
    int nsteps = L - c * CL_;
    nsteps = nsteps < 0 ? 0 : (nsteps > CL_ ? CL_ : nsteps);

    unsigned short (*slab)[136] = pbuf[w];
    float sc0 = 0.0f, sc1 = 0.0f;   // log-scale for this lane's 2 columns

    for (int s = 0; s < nsteps; ++s) {
        // B-fragments from own slab: B[k = 8g+j][n = ci], cols {ci, 16+ci}
        bf16x8 Bf[4][2];
        #pragma unroll
        for (int kt = 0; kt < 4; ++kt) {
            Bf[kt][0] = *(const bf16x8*)&slab[ci][32 * kt + 8 * g];
            Bf[kt][1] = *(const bf16x8*)&slab[16 + ci][32 * kt + 8 * g];
        }
        const float* eyp = eybuf + s * K_ + 4 * g;

        f32x4 acc[8][2];
        #pragma unroll
        for (int rt = 0; rt < 8; ++rt) {
            f32x4 a0 = {0.f, 0.f, 0.f, 0.f}, a1 = {0.f, 0.f, 0.f, 0.f};
            #pragma unroll
            for (int kt = 0; kt < 4; ++kt) {
                a0 = __builtin_amdgcn_mfma_f32_16x16x32_bf16(E[rt][kt], Bf[kt][0], a0, 0, 0, 0);
                a1 = __builtin_amdgcn_mfma_f32_16x16x32_bf16(E[rt][kt], Bf[kt][1], a1, 0, 0, 0);
            }
            f32x4 ey = *(const f32x4*)(eyp + 16 * rt);   // rows 16rt+4g..+3
            acc[rt][0] = a0 * ey;
            acc[rt][1] = a1 * ey;
        }

        // per-column sums (rows partition over g): in-lane + xor16 + xor32
        f32x4 sv0 = acc[0][0], sv1 = acc[0][1];
        #pragma unroll
        for (int rt = 1; rt < 8; ++rt) { sv0 += acc[rt][0]; sv1 += acc[rt][1]; }
        float S0 = (sv0.x + sv0.y) + (sv0.z + sv0.w);
        float S1 = (sv1.x + sv1.y) + (sv1.z + sv1.w);
        S0 += __shfl_xor(S0, 16); S0 += __shfl_xor(S0, 32);
        S1 += __shfl_xor(S1, 16); S1 += __shfl_xor(S1, 32);
        float r0 = __builtin_amdgcn_rcpf(S0);
        float r1 = __builtin_amdgcn_rcpf(S1);
        sc0 += __logf(S0); sc1 += __logf(S1);

        // rescale, pack bf16, write back in-place (per-wave slab, no barrier)
        #pragma unroll
        for (int rt = 0; rt < 8; ++rt) {
            f32x4 v0 = acc[rt][0] * r0, v1 = acc[rt][1] * r1;
            uint2 d0 = make_uint2(pkbf16(v0.x, v0.y), pkbf16(v0.z, v0.w));
            uint2 d1 = make_uint2(pkbf16(v1.x, v1.y), pkbf16(v1.z, v1.w));
            *(uint2*)&slab[ci][16 * rt + 4 * g]      = d0;
            *(uint2*)&slab[16 + ci][16 * rt + 4 * g] = d1;
        }
    }

    // ---- per-column log scales ----
    if (g == 0) {
        scalesWS[bc * K_ + 32 * w + ci]      = sc0;
        scalesWS[bc * K_ + 32 * w + 16 + ci] = sc1;
    }

    __syncthreads();   // all slabs final before cross-wave export

    // ---- export P~ row-major bf16: gm[m*128 + col] = slab[col][m] ----
    {
        unsigned short* gm = matsWS + (size_t)bc * (K_ * K_);
        const int cc = tid >> 1, h = tid & 1;
        const unsigned short* colp = &pbuf[cc >> 5][cc & 31][64 * h];
        unsigned short tmp[64];
        #pragma unroll
        for (int q = 0; q < 8; ++q)
            *(bf16x8*)&tmp[8 * q] = *(const bf16x8*)&colp[8 * q];
        unsigned short* gmb = gm + cc + (size_t)(64 * h) * K_;
        #pragma unroll
        for (int j = 0; j < 64; ++j) gmb[(size_t)j * K_] = tmp[j];
    }
}

// ---------------- Phase 2: combine --------------------------------------
// One block per batch: v <- P_c * (exp(s_c + log v - m)) per chunk, MFMA
// matvec with A row 0 = v~ (B = P_c row-major = B[k][n] = P_c[n][k]).
__global__ __launch_bounds__(256) void crf_combine_kernel(
    const unsigned short* __restrict__ mats,
    const float* __restrict__ scales,
    float* __restrict__ out)
{
    const int b   = blockIdx.x;
    const int tid = threadIdx.x;
    const int w   = tid >> 6;
    const int lane = tid & 63;
    const int g   = lane >> 4;
    const int ci  = lane & 15;

    __shared__ __align__(16) unsigned short matS[2][K_ * K_];  // 64 KB dbuf
    __shared__ float vS[K_], tS[K_], redS;
    __shared__ __align__(16) unsigned short vtH[K_];

    auto dma = [&](int c) {
        const unsigned short* src = mats + (size_t)(b * C_ + c) * (K_ * K_);
        #pragma unroll
        for (int q = 0; q < 8; ++q)
            __builtin_amdgcn_global_load_lds(
                (gas1_t)(src + (w * 8 + q) * 512 + lane * 8),
                (las3_t)(&matS[c & 1][(w * 8 + q) * 512]), 16, 0, 0);
    };

    dma(0);
    if (tid < K_) vS[tid] = (tid == 2) ? 1.0f : 0.0f;   // one-hot SOS
    float cacc = 0.0f;

    for (int c = 0; c < C_; ++c) {
        asm volatile("s_waitcnt vmcnt(0)" ::: "memory");  // chunk c landed
        __syncthreads();                                  // all waves' DMA done; c-1 reads done
        if (c + 1 < C_) dma(c + 1);                       // prefetch into other buffer

        if (tid < K_) tS[tid] = scales[(b * C_ + c) * K_ + tid] + __logf(vS[tid]);
        __syncthreads();
        if (w == 0) {
            float a = fmaxf(tS[lane], tS[lane + 64]);
            a = fmaxf(a, __shfl_xor(a, 1));
            a = fmaxf(a, __shfl_xor(a, 2));
            a = fmaxf(a, __shfl_xor(a, 4));
            a = fmaxf(a, __shfl_xor(a, 8));
            a = fmaxf(a, __shfl_xor(a, 16));
            a = fmaxf(a, __shfl_xor(a, 32));
            if (lane == 0) redS = a;
        }
        __syncthreads();
        const float m = redS;
        if (tid < K_)
            vtH[tid] = (unsigned short)bf16rne(__expf(tS[tid] - m));
        __syncthreads();

        const bf16x8 zero = {};
        f32x4 acc0 = {0.f, 0.f, 0.f, 0.f}, acc1 = {0.f, 0.f, 0.f, 0.f};
        #pragma unroll
        for (int kt = 0; kt < 4; ++kt) {
            bf16x8 Af = *(const bf16x8*)&vtH[32 * kt + 8 * g];
            if (ci != 0) Af = zero;                    // A row 0 = v~, rest 0
            const unsigned short* mp = &matS[c & 1][ci * K_ + 32 * kt + 8 * g];
            bf16x8 B0 = *(const bf16x8*)(mp + (size_t)(16 * (2 * w)) * K_);
            bf16x8 B1 = *(const bf16x8*)(mp + (size_t)(16 * (2 * w + 1)) * K_);
            acc0 = __builtin_amdgcn_mfma_f32_16x16x32_bf16(Af, B0, acc0, 0, 0, 0);
            acc1 = __builtin_amdgcn_mfma_f32_16x16x32_bf16(Af, B1, acc1, 0, 0, 0);
        }
        if (g == 0) {                                  // D row0 = g==0, reg0
            vS[16 * (2 * w)     + ci] = acc0.x;
            vS[16 * (2 * w + 1) + ci] = acc1.x;
        }
        cacc += m;
    }

    __syncthreads();
    if (w == 0) {
        float s2 = vS[lane] + vS[lane + 64];
        s2 += __shfl_xor(s2, 1);
        s2 += __shfl_xor(s2, 2);
        s2 += __shfl_xor(s2, 4);
        s2 += __shfl_xor(s2, 8);
        s2 += __shfl_xor(s2, 16);
        s2 += __shfl_xor(s2, 32);
        if (lane == 0) out[b] = cacc + __logf(s2);
    }
}

extern "C" void kernel_launch(void* const* d_in, const int* in_sizes, int n_in,
                              void* d_out, int out_size, void* d_ws, size_t ws_size,
                              hipStream_t stream) {
    const float* y     = (const float*)d_in[0];   // (B, T, K) fp32
    const float* mask  = (const float*)d_in[1];   // (B, T)    fp32 0/1
    const float* trans = (const float*)d_in[2];   // (K, K)    fp32
    float* out = (float*)d_out;                    // (B,)      fp32

    unsigned short* mats = (unsigned short*)d_ws;                       // 512*128*128 bf16 = 16 MiB
    float* scales = (float*)((char*)d_ws + (size_t)B_ * C_ * K_ * K_ * 2); // 512*128 f32

    crf_chunk_kernel<<<B_ * C_, 256, 0, stream>>>(y, mask, trans, mats, scales);
    crf_combine_kernel<<<B_, 256, 0, stream>>>(mats, scales, out);
}

// Round 6
// 162.467 us; speedup vs baseline: 1.4990x; 1.0657x over previous
//
#include <hip/hip_runtime.h>
#include <math.h>

#define B_ 64
#define T_ 256
#define K_ 128
#define C_ 8           // chunks per batch
#define CL_ 32         // chunk length

typedef const __attribute__((address_space(1))) void* gas1_t;
typedef __attribute__((address_space(3))) void* las3_t;
typedef float  f32x4  __attribute__((ext_vector_type(4)));
typedef short  bf16x8 __attribute__((ext_vector_type(8)));

static __device__ __forceinline__ unsigned int bf16rne(float x) {
    unsigned int u = __builtin_bit_cast(unsigned int, x);
    return (u + 0x7FFFu + ((u >> 16) & 1u)) >> 16;
}
static __device__ __forceinline__ unsigned int pkbf16(float a, float b) {
    return bf16rne(a) | (bf16rne(b) << 16);
}
// truncating bf16x2 pack: 2-3 VALU ops, bias ~2^-9 (fine vs threshold)
static __device__ __forceinline__ unsigned int pktrunc(float a, float b) {
    unsigned int ua = __builtin_bit_cast(unsigned int, a);
    unsigned int ub = __builtin_bit_cast(unsigned int, b);
    return (ua >> 16) | (ub & 0xFFFF0000u);
}

// ---------------- Phase 1: chunk products -------------------------------
// Block (b,c): P_c = prod_t diag(exp(y_t))*E, deferred per-column rescale.
// Slab layout (per wave, 32 cols): slab[col][m] with the 8-short chunk
// q=m>>3 stored at q^(col&15)  -> XOR swizzle kills the 8-way bank conflicts
// of the R4 padded layout. Writeback scaled by PREVIOUS step's column sums
// (r off the critical path). Export via LDS transpose -> coalesced stores.
__global__ __launch_bounds__(256, 2) void crf_chunk_kernel(
    const float* __restrict__ y,
    const float* __restrict__ mask,
    const float* __restrict__ trans,
    unsigned short* __restrict__ matsWS,
    float* __restrict__ scalesWS)
{
    const int bc  = blockIdx.x;           // b*C_ + c
    const int b   = bc >> 3;
    const int c   = bc & 7;
    const int tid = threadIdx.x;
    const int w   = tid >> 6;             // wave 0..3 -> columns [32w, 32w+32)
    const int lane = tid & 63;
    const int g   = lane >> 4;            // quad 0..3
    const int ci  = lane & 15;

    __shared__ __align__(16) float eybuf[CL_ * K_];            // 16 KB (reused as export stage)
    __shared__ __align__(16) unsigned short pbuf[4][32][128];  // 32 KB swizzled slabs
    __shared__ int lenS[4];

    // ---- DMA y chunk into LDS ----
    const float* gy = y + ((size_t)b * T_ + c * CL_) * K_;
    #pragma unroll
    for (int q = 0; q < 4; ++q) {
        const int seg = w * 4 + q;
        __builtin_amdgcn_global_load_lds((gas1_t)(gy + seg * 256 + lane * 4),
                                         (las3_t)(eybuf + seg * 256), 16, 0, 0);
    }

    // ---- sequence length (mask contiguous 1.0/0.0) ----
    float mval = mask[b * T_ + tid];
    unsigned long long bal = __ballot(mval != 0.0f);
    if (lane == 0) lenS[w] = __popcll(bal);

    // ---- E as A-fragments: A[m=ci][k=8g+j], RNE bf16 (one-time) ----
    bf16x8 E[8][4];
    #pragma unroll
    for (int rt = 0; rt < 8; ++rt) {
        const float* tp = trans + (16 * rt + ci) * K_;
        #pragma unroll
        for (int kt = 0; kt < 4; ++kt) {
            f32x4 a = *(const f32x4*)(tp + 32 * kt + 8 * g);
            f32x4 bq = *(const f32x4*)(tp + 32 * kt + 8 * g + 4);
            uint2 u0 = make_uint2(pkbf16(__expf(a.x), __expf(a.y)),
                                  pkbf16(__expf(a.z), __expf(a.w)));
            uint2 u1 = make_uint2(pkbf16(__expf(bq.x), __expf(bq.y)),
                                  pkbf16(__expf(bq.z), __expf(bq.w)));
            uint4 uu = make_uint4(u0.x, u0.y, u1.x, u1.y);
            E[rt][kt] = __builtin_bit_cast(bf16x8, uu);
        }
    }

    // ---- zero slabs ----
    for (int i = tid; i < 4 * 32 * 128; i += 256) ((unsigned short*)pbuf)[i] = 0;

    asm volatile("s_waitcnt vmcnt(0)" ::: "memory");   // y DMA landed
    __syncthreads();

    // identity init (swizzled) + ey = exp(y) in place
    if (tid < K_) {
        const int col = tid & 31;
        const int qph = (tid >> 3) ^ (tid & 15);
        pbuf[tid >> 5][col][(qph << 3) | (tid & 7)] = 0x3F80;  // bf16 1.0
    }
    for (int i = tid; i < CL_ * K_; i += 256) eybuf[i] = __expf(eybuf[i]);
    __syncthreads();

    const int L = lenS[0] + lenS[1] + lenS[2] + lenS[3];
    int nsteps = L - c * CL_;
    nsteps = nsteps < 0 ? 0 : (nsteps > CL_ ? CL_ : nsteps);

    unsigned short (*slab)[128] = pbuf[w];
    float sc0 = 0.0f, sc1 = 0.0f;      // accumulated log column scales
    float r0 = 1.0f, r1 = 1.0f;        // deferred rescale (prev step's sums)
    float ls0 = 0.0f, ls1 = 0.0f;

    for (int s = 0; s < nsteps; ++s) {
        sc0 += ls0; sc1 += ls1;        // accumulate all but the last step's sum

        // B-fragments from own slab (swizzled, in-order DS pipe => RAW safe)
        bf16x8 Bf0[4], Bf1[4];
        #pragma unroll
        for (int kt = 0; kt < 4; ++kt) {
            const int qph = (((4 * kt + g) ^ ci) << 3);
            Bf0[kt] = *(const bf16x8*)&slab[ci][qph];
            Bf1[kt] = *(const bf16x8*)&slab[16 + ci][qph];
        }
        const float* eyp = eybuf + s * K_ + 4 * g;

        f32x4 sv0 = {0.f, 0.f, 0.f, 0.f}, sv1 = {0.f, 0.f, 0.f, 0.f};
        #pragma unroll
        for (int rt = 0; rt < 8; ++rt) {
            f32x4 a0 = {0.f, 0.f, 0.f, 0.f}, a1 = {0.f, 0.f, 0.f, 0.f};
            #pragma unroll
            for (int kt = 0; kt < 4; ++kt) {
                a0 = __builtin_amdgcn_mfma_f32_16x16x32_bf16(E[rt][kt], Bf0[kt], a0, 0, 0, 0);
                a1 = __builtin_amdgcn_mfma_f32_16x16x32_bf16(E[rt][kt], Bf1[kt], a1, 0, 0, 0);
            }
            f32x4 ey = *(const f32x4*)(eyp + 16 * rt);   // rows 16rt+4g..+3
            a0 *= ey; a1 *= ey;
            sv0 += a0; sv1 += a1;                        // raw column partial sums
            f32x4 w0v = a0 * r0, w1v = a1 * r1;          // deferred rescale
            const int qph = ((2 * rt + (g >> 1)) ^ ci) << 3;
            const int eo  = 4 * (g & 1);
            uint2 d0 = make_uint2(pktrunc(w0v.x, w0v.y), pktrunc(w0v.z, w0v.w));
            uint2 d1 = make_uint2(pktrunc(w1v.x, w1v.y), pktrunc(w1v.z, w1v.w));
            *(uint2*)&slab[ci][qph + eo]      = d0;
            *(uint2*)&slab[16 + ci][qph + eo] = d1;
        }

        // stored-column sums (off critical path: only next step's writeback uses r)
        float S0 = (sv0.x + sv0.y) + (sv0.z + sv0.w);
        float S1 = (sv1.x + sv1.y) + (sv1.z + sv1.w);
        S0 += __shfl_xor(S0, 16); S0 += __shfl_xor(S0, 32);
        S1 += __shfl_xor(S1, 16); S1 += __shfl_xor(S1, 32);
        S0 *= r0; S1 *= r1;                              // sums of what we stored
        ls0 = __logf(S0); ls1 = __logf(S1);
        r0 = __builtin_amdgcn_rcpf(S0);
        r1 = __builtin_amdgcn_rcpf(S1);
    }

    // ---- per-column log scales: true P = stored * diag(exp(sc)) ----
    if (g == 0) {
        scalesWS[bc * K_ + 32 * w + ci]      = sc0;
        scalesWS[bc * K_ + 32 * w + 16 + ci] = sc1;
    }

    __syncthreads();   // all slabs final

    // ---- export P row-major bf16 via staged LDS transpose (coalesced) ----
    {
        unsigned short* stage = (unsigned short*)eybuf;   // 16 KB = 64 rows
        unsigned short* gm = matsWS + (size_t)bc * (K_ * K_);
        const int j  = tid & 127;      // source column
        const int mq = tid >> 7;       // 0..1
        #pragma unroll
        for (int p = 0; p < 2; ++p) {  // row halves [0,64), [64,128)
            if (p) __syncthreads();    // stage reuse
            #pragma unroll
            for (int qq = 0; qq < 4; ++qq) {
                const int ql = 8 * p + 4 * mq + qq;
                bf16x8 v = *(const bf16x8*)&pbuf[j >> 5][j & 31][(ql ^ (j & 15)) << 3];
                const int mb = (8 * ql) & 63;   // local row base
                #pragma unroll
                for (int e = 0; e < 8; ++e)
                    stage[(mb + e) * K_ + j] = (unsigned short)v[e];
            }
            __syncthreads();
            #pragma unroll
            for (int r = 0; r < 4; ++r) {       // 16 KB out, dwordx4 coalesced
                const int idx = 8 * (256 * r + tid);
                *(bf16x8*)(gm + p * 8192 + idx) = *(const bf16x8*)&stage[idx];
            }
        }
    }
}

// ---------------- Phase 2: combine --------------------------------------
// One block per batch. DMA of chunk c+1 issued BEFORE waiting on chunk c
// (vmcnt(8)) so transfers hide under compute. Scales preloaded to LDS.
__global__ __launch_bounds__(256) void crf_combine_kernel(
    const unsigned short* __restrict__ mats,
    const float* __restrict__ scales,
    float* __restrict__ out)
{
    const int b   = blockIdx.x;
    const int tid = threadIdx.x;
    const int w   = tid >> 6;
    const int lane = tid & 63;
    const int g   = lane >> 4;
    const int ci  = lane & 15;

    __shared__ __align__(16) unsigned short matS[2][K_ * K_];  // 64 KB dbuf
    __shared__ float scS[C_ * K_];                             // 4 KB all scales
    __shared__ float vS[K_];
    __shared__ __align__(16) unsigned short vtH[K_];

    auto dma = [&](int c) {
        const unsigned short* src = mats + (size_t)(b * C_ + c) * (K_ * K_);
        #pragma unroll
        for (int q = 0; q < 8; ++q)
            __builtin_amdgcn_global_load_lds(
                (gas1_t)(src + (w * 8 + q) * 512 + lane * 8),
                (las3_t)(&matS[c & 1][(w * 8 + q) * 512]), 16, 0, 0);
    };

    dma(0);
    {   // preload all 8 chunks' scales
        f32x4 sv = *(const f32x4*)(scales + (size_t)b * C_ * K_ + tid * 4);
        *(f32x4*)&scS[tid * 4] = sv;
    }
    if (tid < K_) vS[tid] = (tid == 2) ? 1.0f : 0.0f;   // one-hot SOS
    float cacc = 0.0f;

    for (int c = 0; c < C_; ++c) {
        __syncthreads();                       // (A) prev reads of buf (c+1)&1 done
        if (c + 1 < C_) {
            dma(c + 1);                        // prefetch first...
            asm volatile("s_waitcnt vmcnt(8)" ::: "memory");   // ...then wait chunk c
        } else {
            asm volatile("s_waitcnt vmcnt(0)" ::: "memory");
        }
        __syncthreads();                       // (B) chunk c visible to all waves

        // t = scale + log v ; wave-redundant max (no extra barrier)
        float t0 = scS[c * K_ + lane]      + __logf(vS[lane]);
        float t1 = scS[c * K_ + lane + 64] + __logf(vS[lane + 64]);
        float m = fmaxf(t0, t1);
        m = fmaxf(m, __shfl_xor(m, 1));
        m = fmaxf(m, __shfl_xor(m, 2));
        m = fmaxf(m, __shfl_xor(m, 4));
        m = fmaxf(m, __shfl_xor(m, 8));
        m = fmaxf(m, __shfl_xor(m, 16));
        m = fmaxf(m, __shfl_xor(m, 32));
        if (w == 0) {
            vtH[lane]      = (unsigned short)bf16rne(__expf(t0 - m));
            vtH[lane + 64] = (unsigned short)bf16rne(__expf(t1 - m));
        }
        __syncthreads();                       // (C) vtH visible

        const bf16x8 zero = {};
        f32x4 acc0 = {0.f, 0.f, 0.f, 0.f}, acc1 = {0.f, 0.f, 0.f, 0.f};
        #pragma unroll
        for (int kt = 0; kt < 4; ++kt) {
            bf16x8 Af = *(const bf16x8*)&vtH[32 * kt + 8 * g];
            if (ci != 0) Af = zero;            // A row 0 = v~, rest 0
            const unsigned short* mp = &matS[c & 1][ci * K_ + 32 * kt + 8 * g];
            bf16x8 B0 = *(const bf16x8*)(mp + (size_t)(16 * (2 * w)) * K_);
            bf16x8 B1 = *(const bf16x8*)(mp + (size_t)(16 * (2 * w + 1)) * K_);
            acc0 = __builtin_amdgcn_mfma_f32_16x16x32_bf16(Af, B0, acc0, 0, 0, 0);
            acc1 = __builtin_amdgcn_mfma_f32_16x16x32_bf16(Af, B1, acc1, 0, 0, 0);
        }
        if (g == 0) {                          // D row0 = g==0, reg 0
            vS[16 * (2 * w)     + ci] = acc0.x;
            vS[16 * (2 * w + 1) + ci] = acc1.x;
        }
        cacc += m;
    }

    __syncthreads();
    if (w == 0) {
        float s2 = vS[lane] + vS[lane + 64];
        s2 += __shfl_xor(s2, 1);
        s2 += __shfl_xor(s2, 2);
        s2 += __shfl_xor(s2, 4);
        s2 += __shfl_xor(s2, 8);
        s2 += __shfl_xor(s2, 16);
        s2 += __shfl_xor(s2, 32);
        if (lane == 0) out[b] = cacc + __logf(s2);
    }
}

extern "C" void kernel_launch(void* const* d_in, const int* in_sizes, int n_in,
                              void* d_out, int out_size, void* d_ws, size_t ws_size,
                              hipStream_t stream) {
    const float* y     = (const float*)d_in[0];   // (B, T, K) fp32
    const float* mask  = (const float*)d_in[1];   // (B, T)    fp32 0/1
    const float* trans = (const float*)d_in[2];   // (K, K)    fp32
    float* out = (float*)d_out;                    // (B,)      fp32

    unsigned short* mats = (unsigned short*)d_ws;  // 512*128*128 bf16 = 16 MiB
    float* scales = (float*)((char*)d_ws + (size_t)B_ * C_ * K_ * K_ * 2);

    crf_chunk_kernel<<<B_ * C_, 256, 0, stream>>>(y, mask, trans, mats, scales);
    crf_combine_kernel<<<B_, 256, 0, stream>>>(mats, scales, out);
}